// Round 1
// baseline (1431.371 us; speedup 1.0000x reference)
//
#include <hip/hip_runtime.h>
#include <hip/hip_bf16.h>
#include <math.h>

constexpr int CB = 2;
constexpr int CS = 1024;
constexpr int CD = 1024;
constexpr int CDI = 2048;
constexpr int CN = 16;
constexpr int CNCH = 16;   // chunks for scan
constexpr int CCL = 64;    // chunk length = CS / CNCH

// ---------------- LayerNorm ----------------
__global__ __launch_bounds__(256)
void ln_kernel(const float* __restrict__ x, const float* __restrict__ g,
               const float* __restrict__ bb, float* __restrict__ out) {
  int row = blockIdx.x;
  const float4* xr = (const float4*)(x + (size_t)row * CD);
  float4 v = xr[threadIdx.x];
  float s = v.x + v.y + v.z + v.w;
  float ss = v.x * v.x + v.y * v.y + v.z * v.z + v.w * v.w;
#pragma unroll
  for (int o = 1; o < 64; o <<= 1) { s += __shfl_xor(s, o); ss += __shfl_xor(ss, o); }
  __shared__ float sb[4], ssb[4];
  int wid = threadIdx.x >> 6;
  if ((threadIdx.x & 63) == 0) { sb[wid] = s; ssb[wid] = ss; }
  __syncthreads();
  s = sb[0] + sb[1] + sb[2] + sb[3];
  ss = ssb[0] + ssb[1] + ssb[2] + ssb[3];
  float mu = s * (1.f / CD);
  float var = ss * (1.f / CD) - mu * mu;
  float rstd = rsqrtf(var + 1e-5f);
  float4 gv = ((const float4*)g)[threadIdx.x];
  float4 bv = ((const float4*)bb)[threadIdx.x];
  float4 o;
  o.x = (v.x - mu) * rstd * gv.x + bv.x;
  o.y = (v.y - mu) * rstd * gv.y + bv.y;
  o.z = (v.z - mu) * rstd * gv.z + bv.z;
  o.w = (v.w - mu) * rstd * gv.w + bv.w;
  ((float4*)(out + (size_t)row * CD))[threadIdx.x] = o;
}

// ---------------- SGEMM: C = act(A@B + bias + resid) ----------------
// 256 threads; BM/TM = BN/TN = 16. Guards only on N (cols); M,K assumed multiples.
template<int BM, int BN, int BK, int TM, int TN, int ACT>
__global__ __launch_bounds__(256)
void sgemm_kernel(const float* __restrict__ A, int lda,
                  const float* __restrict__ Bp, int ldb,
                  const float* __restrict__ bias,
                  const float* __restrict__ resid, int ldr,
                  float* __restrict__ C, int ldc,
                  int M, int N, int K) {
  __shared__ float As[BK][BM];
  __shared__ float Bs[BK][BN];
  const int tid = threadIdx.x;
  const int bm = blockIdx.y * BM;
  const int bn = blockIdx.x * BN;
  const int tx = tid & 15;
  const int ty = tid >> 4;
  constexpr int ATR = BK / 4;  // threads per A-tile row
  constexpr int BTR = BN / 4;  // threads per B-tile row
  const int a_row = tid / ATR, a_col = (tid % ATR) * 4;
  const int b_row = tid / BTR, b_col = (tid % BTR) * 4;
  float acc[TM][TN];
#pragma unroll
  for (int i = 0; i < TM; ++i)
#pragma unroll
    for (int j = 0; j < TN; ++j) acc[i][j] = 0.f;

  for (int k0 = 0; k0 < K; k0 += BK) {
    float4 av = *(const float4*)(A + (size_t)(bm + a_row) * lda + (k0 + a_col));
    As[a_col + 0][a_row] = av.x;
    As[a_col + 1][a_row] = av.y;
    As[a_col + 2][a_row] = av.z;
    As[a_col + 3][a_row] = av.w;
    int gc = bn + b_col;
    float4 bv = make_float4(0.f, 0.f, 0.f, 0.f);
    if (gc < N) bv = *(const float4*)(Bp + (size_t)(k0 + b_row) * ldb + gc);
    *(float4*)&Bs[b_row][b_col] = bv;
    __syncthreads();
#pragma unroll
    for (int kk = 0; kk < BK; ++kk) {
      float ra[TM], rb[TN];
#pragma unroll
      for (int i = 0; i < TM; ++i) ra[i] = As[kk][ty * TM + i];
#pragma unroll
      for (int j = 0; j < TN; ++j) rb[j] = Bs[kk][tx * TN + j];
#pragma unroll
      for (int i = 0; i < TM; ++i)
#pragma unroll
        for (int j = 0; j < TN; ++j) acc[i][j] = fmaf(ra[i], rb[j], acc[i][j]);
    }
    __syncthreads();
  }
#pragma unroll
  for (int i = 0; i < TM; ++i) {
    int r = bm + ty * TM + i;
#pragma unroll
    for (int j = 0; j < TN; ++j) {
      int c = bn + tx * TN + j;
      if (c < N) {
        float v = acc[i][j];
        if (bias) v += bias[c];
        if (resid) v += resid[(size_t)r * ldr + c];
        if (ACT == 1) v = (v > 20.f) ? v : log1pf(__expf(v));  // softplus
        C[(size_t)r * ldc + c] = v;
      }
    }
  }
}

// ---------------- causal depthwise conv (K=4) + silu ----------------
__global__ __launch_bounds__(256)
void conv_silu_kernel(const float* __restrict__ xp, const float* __restrict__ w,
                      const float* __restrict__ cb, float* __restrict__ xc) {
  int idx = blockIdx.x * 256 + threadIdx.x;  // over CB*CS*CDI = 4M
  int d = idx & (CDI - 1);
  int t = (idx >> 11) & (CS - 1);
  int b = idx >> 21;
  const float* col = xp + (size_t)b * CS * CDI + d;
  float acc = cb[d];
#pragma unroll
  for (int k = 0; k < 4; ++k) {
    int tt = t - 3 + k;
    if (tt >= 0) acc = fmaf(col[(size_t)tt * CDI], w[d * 4 + k], acc);
  }
  xc[idx] = acc * (1.f / (1.f + __expf(-acc)));
}

// ---------------- selective scan, 3-phase chunked ----------------
// thread -> (b, chunk, d, n): n=gid&15, d=(gid>>4)&2047, c=(gid>>15)&15, b=gid>>19
__global__ __launch_bounds__(256)
void scan_phase1(const float* __restrict__ dt, const float* __restrict__ xc,
                 const float* __restrict__ dbc, const float* __restrict__ A_log,
                 float* __restrict__ P, float* __restrict__ Q) {
  int gid = blockIdx.x * 256 + threadIdx.x;
  int n = gid & 15;
  int d = (gid >> 4) & (CDI - 1);
  int c = (gid >> 15) & (CNCH - 1);
  int b = gid >> 19;
  float acoef = -__expf(A_log[d * CN + n]);
  float Pv = 1.f, Qv = 0.f;
  size_t rowbase = (size_t)b * CS + c * CCL;
  for (int i = 0; i < CCL; ++i) {
    size_t r = rowbase + i;
    float dtv = dt[r * CDI + d];
    float xcv = xc[r * CDI + d];
    float bsv = dbc[r * 96 + 64 + n];
    float a = __expf(dtv * acoef);
    Pv *= a;
    Qv = fmaf(a, Qv, dtv * xcv * bsv);
  }
  size_t o = (((size_t)b * CNCH + c) * CDI + d) * CN + n;
  P[o] = Pv; Q[o] = Qv;
}

__global__ __launch_bounds__(256)
void scan_phase2(const float* __restrict__ P, const float* __restrict__ Q,
                 float* __restrict__ HS) {
  int gid = blockIdx.x * 256 + threadIdx.x;  // CB*CDI*CN = 65536
  int n = gid & 15;
  int d = (gid >> 4) & (CDI - 1);
  int b = gid >> 15;
  float h = 0.f;
  for (int c = 0; c < CNCH; ++c) {
    size_t o = (((size_t)b * CNCH + c) * CDI + d) * CN + n;
    float p = P[o], q = Q[o];
    HS[o] = h;
    h = fmaf(p, h, q);
  }
}

__global__ __launch_bounds__(256)
void scan_phase3(const float* __restrict__ dt, const float* __restrict__ xc,
                 const float* __restrict__ dbc, const float* __restrict__ A_log,
                 const float* __restrict__ HS, const float* __restrict__ z,
                 const float* __restrict__ Dskip, float* __restrict__ y2) {
  int gid = blockIdx.x * 256 + threadIdx.x;
  int n = gid & 15;
  int d = (gid >> 4) & (CDI - 1);
  int c = (gid >> 15) & (CNCH - 1);
  int b = gid >> 19;
  float acoef = -__expf(A_log[d * CN + n]);
  size_t o = (((size_t)b * CNCH + c) * CDI + d) * CN + n;
  float h = HS[o];
  float dsk = Dskip[d];
  size_t rowbase = (size_t)b * CS + c * CCL;
  for (int i = 0; i < CCL; ++i) {
    size_t r = rowbase + i;
    float dtv = dt[r * CDI + d];
    float xcv = xc[r * CDI + d];
    float bsv = dbc[r * 96 + 64 + n];
    float csv = dbc[r * 96 + 80 + n];
    float a = __expf(dtv * acoef);
    h = fmaf(a, h, dtv * xcv * bsv);
    float yv = h * csv;
    yv += __shfl_xor(yv, 1);
    yv += __shfl_xor(yv, 2);
    yv += __shfl_xor(yv, 4);
    yv += __shfl_xor(yv, 8);
    if (n == 0) {
      float zv = z[r * CDI + d];
      float sz = zv * (1.f / (1.f + __expf(-zv)));
      y2[r * CDI + d] = (yv + xcv * dsk) * sz;
    }
  }
}

// ---------------- soliton stencil ----------------
__global__ __launch_bounds__(256)
void soliton_kernel(const float* __restrict__ uu, const float* __restrict__ gates,
                    const float* __restrict__ alpha, float* __restrict__ sol) {
  int idx = blockIdx.x * 256 + threadIdx.x;  // CB*CS*CD = 2M
  int d = idx & (CD - 1);
  int t = (idx >> 10) & (CS - 1);
  int b = idx >> 20;
  int h = d >> 6;
  const float* base = uu + (size_t)b * CS * CD + d;
  int tm2 = max(t - 2, 0), tm1 = max(t - 1, 0);
  int tp1 = min(t + 1, CS - 1), tp2 = min(t + 2, CS - 1);
  float um2 = base[(size_t)tm2 * CD];
  float um1 = base[(size_t)tm1 * CD];
  float u0  = base[(size_t)t   * CD];
  float up1 = base[(size_t)tp1 * CD];
  float up2 = base[(size_t)tp2 * CD];
  float ux   = (up1 - um1) * 0.5f;
  float uxx  = up1 - 2.f * u0 + um1;
  float uxxx = (up2 - 2.f * up1 + 2.f * um1 - um2) * 0.5f;
  float sg = sinf(u0);
  float kdv = -6.f * u0 * ux - uxxx;
  float hj = (1.f + alpha[h] * u0) * uxx;
  float du = gates[h * 3 + 0] * sg + gates[h * 3 + 1] * kdv + gates[h * 3 + 2] * hj;
  sol[idx] = 0.1f * du;
}

extern "C" void kernel_launch(void* const* d_in, const int* in_sizes, int n_in,
                              void* d_out, int out_size, void* d_ws, size_t ws_size,
                              hipStream_t stream) {
  const float* x      = (const float*)d_in[0];
  const float* ln1_g  = (const float*)d_in[1];
  const float* ln1_b  = (const float*)d_in[2];
  const float* W_in   = (const float*)d_in[3];
  const float* b_in   = (const float*)d_in[4];
  const float* conv_w = (const float*)d_in[5];
  const float* conv_b = (const float*)d_in[6];
  const float* W_xp   = (const float*)d_in[7];
  const float* W_dt   = (const float*)d_in[8];
  const float* b_dt   = (const float*)d_in[9];
  const float* A_log  = (const float*)d_in[10];
  const float* D_skip = (const float*)d_in[11];
  const float* W_out  = (const float*)d_in[12];
  const float* b_out  = (const float*)d_in[13];
  const float* ln2_g  = (const float*)d_in[14];
  const float* ln2_b  = (const float*)d_in[15];
  const float* W_si   = (const float*)d_in[16];
  const float* b_si   = (const float*)d_in[17];
  const float* gates  = (const float*)d_in[18];
  const float* alpha  = (const float*)d_in[19];
  const float* W_so   = (const float*)d_in[20];
  const float* b_so   = (const float*)d_in[21];
  float* out = (float*)d_out;

  float* ws = (float*)d_ws;
  size_t off = 0;
  auto alloc = [&](size_t n) { float* p = ws + off; off += n; return p; };
  const size_t BS = (size_t)CB * CS;  // 2048 rows
  float* u   = alloc(BS * CD);             // LN output; reused for LN2 output
  float* xp  = alloc(BS * CDI);            // conv input; reused as y2
  float* z   = alloc(BS * CDI);
  float* xc  = alloc(BS * CDI);            // reused as uu
  float* dbc = alloc(BS * 96);
  float* dt  = alloc(BS * CDI);
  float* Pb  = alloc((size_t)CB * CNCH * CDI * CN);  // P (reused w/ Qb as sol)
  float* Qb  = alloc((size_t)CB * CNCH * CDI * CN);
  float* HS  = alloc((size_t)CB * CNCH * CDI * CN);
  float* y2  = xp;
  float* uu  = xc;
  float* sol = Pb;  // 2M floats spanning Pb+Qb (contiguous)

  dim3 blk(256);

  // 1. u = LN1(x)
  ln_kernel<<<BS, blk, 0, stream>>>(x, ln1_g, ln1_b, u);
  // 2-3. xp|z = u @ W_in + b_in (column halves)
  {
    dim3 g(CDI / 128, BS / 128);
    sgemm_kernel<128,128,8,8,8,0><<<g, blk, 0, stream>>>(u, CD, W_in, 2*CDI, b_in, nullptr, 0, xp, CDI, BS, CDI, CD);
    sgemm_kernel<128,128,8,8,8,0><<<g, blk, 0, stream>>>(u, CD, W_in + CDI, 2*CDI, b_in + CDI, nullptr, 0, z, CDI, BS, CDI, CD);
  }
  // 4. xc = silu(causal depthwise conv(xp) + conv_b)
  conv_silu_kernel<<<(BS * CDI) / 256, blk, 0, stream>>>(xp, conv_w, conv_b, xc);
  // 5. dbc = xc @ W_xp   (N=96 skinny)
  sgemm_kernel<64,64,16,4,4,0><<<dim3(2, BS / 64), blk, 0, stream>>>(xc, CDI, W_xp, 96, nullptr, nullptr, 0, dbc, 96, BS, 96, CDI);
  // 6. dt = softplus(dtr @ W_dt + b_dt), dtr = dbc[:, 0:64]
  sgemm_kernel<128,128,8,8,8,1><<<dim3(CDI / 128, BS / 128), blk, 0, stream>>>(dbc, 96, W_dt, CDI, b_dt, nullptr, 0, dt, CDI, BS, CDI, 64);
  // 7-9. chunked selective scan; phase3 fuses y2 = (y + xc*D_skip)*silu(z)
  scan_phase1<<<(CB * CNCH * CDI * CN) / 256, blk, 0, stream>>>(dt, xc, dbc, A_log, Pb, Qb);
  scan_phase2<<<(CB * CDI * CN) / 256, blk, 0, stream>>>(Pb, Qb, HS);
  scan_phase3<<<(CB * CNCH * CDI * CN) / 256, blk, 0, stream>>>(dt, xc, dbc, A_log, HS, z, D_skip, y2);
  // 10. x1 = x + y2 @ W_out + b_out  -> d_out
  sgemm_kernel<128,128,8,8,8,0><<<dim3(CD / 128, BS / 128), blk, 0, stream>>>(y2, CDI, W_out, CD, b_out, x, CD, out, CD, BS, CD, CDI);
  // 11. v = LN2(x1) -> u
  ln_kernel<<<BS, blk, 0, stream>>>(out, ln2_g, ln2_b, u);
  // 12. uu = v @ W_si + b_si
  sgemm_kernel<128,128,8,8,8,0><<<dim3(CD / 128, BS / 128), blk, 0, stream>>>(u, CD, W_si, CD, b_si, nullptr, 0, uu, CD, BS, CD, CD);
  // 13. sol = 0.1 * du(uu)
  soliton_kernel<<<(BS * CD) / 256, blk, 0, stream>>>(uu, gates, alpha, sol);
  // 14. out = x1 + sol @ W_so + b_so  (per-element read-then-write of d_out is same-thread)
  sgemm_kernel<128,128,8,8,8,0><<<dim3(CD / 128, BS / 128), blk, 0, stream>>>(sol, CD, W_so, CD, b_so, out, CD, out, CD, BS, CD, CD);
}

// Round 2
// 487.271 us; speedup vs baseline: 2.9375x; 2.9375x over previous
//
#include <hip/hip_runtime.h>
#include <hip/hip_bf16.h>
#include <math.h>

typedef unsigned short u16;
typedef __attribute__((ext_vector_type(8))) short short8;
typedef __attribute__((ext_vector_type(4))) float f32x4;

constexpr int CB = 2;
constexpr int CS = 1024;
constexpr int CD = 1024;
constexpr int CDI = 2048;
constexpr int CN = 16;
constexpr int CNCH = 16;   // chunks for scan
constexpr int CCL = 64;    // chunk length = CS / CNCH

__device__ inline u16 f2bf(float v) {
  __hip_bfloat16 h = __float2bfloat16(v);
  return *reinterpret_cast<u16*>(&h);
}

__device__ inline void gload16(const void* g, void* l) {
  __builtin_amdgcn_global_load_lds((const __attribute__((address_space(1))) void*)g,
                                   (__attribute__((address_space(3))) void*)l, 16, 0, 0);
}

// ---------------- transpose + fp32->bf16 convert: in[K][N] -> out[Npad][K] ----------------
__global__ __launch_bounds__(256)
void transpose_bf16_kernel(const float* __restrict__ in, u16* __restrict__ out,
                           int K, int N, int Npad) {
  __shared__ float tile[32][33];
  int n0 = blockIdx.x * 32, k0 = blockIdx.y * 32;
  int tx = threadIdx.x & 31, ty = threadIdx.x >> 5;  // 32 x 8
#pragma unroll
  for (int i = 0; i < 4; ++i) {
    int k = k0 + ty + i * 8, n = n0 + tx;
    tile[ty + i * 8][tx] = (n < N) ? in[(size_t)k * N + n] : 0.f;
  }
  __syncthreads();
#pragma unroll
  for (int i = 0; i < 4; ++i) {
    int n = n0 + ty + i * 8, k = k0 + tx;
    out[(size_t)n * K + k] = f2bf(tile[tx][ty + i * 8]);
  }
}

// ---------------- LayerNorm -> bf16 ----------------
__global__ __launch_bounds__(256)
void ln_kernel(const float* __restrict__ x, const float* __restrict__ g,
               const float* __restrict__ bb, u16* __restrict__ outb) {
  int row = blockIdx.x;
  const float4* xr = (const float4*)(x + (size_t)row * CD);
  float4 v = xr[threadIdx.x];
  float s = v.x + v.y + v.z + v.w;
  float ss = v.x * v.x + v.y * v.y + v.z * v.z + v.w * v.w;
#pragma unroll
  for (int o = 1; o < 64; o <<= 1) { s += __shfl_xor(s, o); ss += __shfl_xor(ss, o); }
  __shared__ float sb[4], ssb[4];
  int wid = threadIdx.x >> 6;
  if ((threadIdx.x & 63) == 0) { sb[wid] = s; ssb[wid] = ss; }
  __syncthreads();
  s = sb[0] + sb[1] + sb[2] + sb[3];
  ss = ssb[0] + ssb[1] + ssb[2] + ssb[3];
  float mu = s * (1.f / CD);
  float var = ss * (1.f / CD) - mu * mu;
  float rstd = rsqrtf(var + 1e-5f);
  float4 gv = ((const float4*)g)[threadIdx.x];
  float4 bv = ((const float4*)bb)[threadIdx.x];
  ushort4 o;
  o.x = f2bf((v.x - mu) * rstd * gv.x + bv.x);
  o.y = f2bf((v.y - mu) * rstd * gv.y + bv.y);
  o.z = f2bf((v.z - mu) * rstd * gv.z + bv.z);
  o.w = f2bf((v.w - mu) * rstd * gv.w + bv.w);
  ((ushort4*)(outb + (size_t)row * CD))[threadIdx.x] = o;
}

// ---------------- bf16 MFMA GEMM: C = act(A @ Bt^T + bias + resid) ----------------
// A [M][K] bf16 row-major (lda=K stride), Bt [Npad][K] bf16 (transposed B), C fp32.
// Tile 128x128, BK=64, 4 waves each owning a 64x64 sub-tile.
// LDS layout: [128 rows][64 k] with 16B-chunk XOR swizzle (chunk ^= row&7) applied on
// the GLOBAL source side (global_load_lds dest is linear) and on the ds_read side.
__global__ __launch_bounds__(256)
void gemm_bf16_kernel(const u16* __restrict__ A, int lda,
                      const u16* __restrict__ Bt, int ldb,
                      const float* __restrict__ bias,
                      const float* __restrict__ resid, int ldr,
                      float* __restrict__ C, int ldc,
                      u16* __restrict__ aux, int auxN,
                      int Nact, int K, int act) {
  __shared__ __align__(16) u16 As[128 * 64];
  __shared__ __align__(16) u16 Bs[128 * 64];
  const int tid = threadIdx.x, lane = tid & 63, wid = tid >> 6;
  const int wr = wid >> 1, wc = wid & 1;
  const int bm = blockIdx.y * 128, bn = blockIdx.x * 128;
  f32x4 acc[4][4] = {};

  for (int k0 = 0; k0 < K; k0 += 64) {
    __syncthreads();  // protect LDS before overwrite
#pragma unroll
    for (int j = 0; j < 4; ++j) {
      int cbase = j * 256 + wid * 64;     // wave-uniform dest chunk base
      int c = cbase + lane;               // this lane's dest chunk
      int row = c >> 3;                   // 8 chunks (128B) per row
      int kc = (c & 7) ^ (row & 7);       // inverse-swizzled source chunk
      gload16(A + (size_t)(bm + row) * lda + k0 + kc * 8, As + cbase * 8);
      gload16(Bt + (size_t)(bn + row) * ldb + k0 + kc * 8, Bs + cbase * 8);
    }
    __syncthreads();  // compiler drains vmcnt(0) before barrier
#pragma unroll
    for (int ks = 0; ks < 64; ks += 32) {
      short8 af[4], bfr[4];
#pragma unroll
      for (int m = 0; m < 4; ++m) {
        int r = wr * 64 + m * 16 + (lane & 15);
        int ch = (lane >> 4) + (ks >> 3);
        af[m] = *(const short8*)&As[r * 64 + ((ch ^ (r & 7)) << 3)];
      }
#pragma unroll
      for (int n = 0; n < 4; ++n) {
        int r = wc * 64 + n * 16 + (lane & 15);
        int ch = (lane >> 4) + (ks >> 3);
        bfr[n] = *(const short8*)&Bs[r * 64 + ((ch ^ (r & 7)) << 3)];
      }
#pragma unroll
      for (int m = 0; m < 4; ++m)
#pragma unroll
        for (int n = 0; n < 4; ++n)
          acc[m][n] = __builtin_amdgcn_mfma_f32_16x16x32_bf16(af[m], bfr[n], acc[m][n], 0, 0, 0);
    }
  }

  const int fr = lane & 15, fq = lane >> 4;
#pragma unroll
  for (int m = 0; m < 4; ++m) {
#pragma unroll
    for (int n = 0; n < 4; ++n) {
#pragma unroll
      for (int j = 0; j < 4; ++j) {
        int row = bm + wr * 64 + m * 16 + fq * 4 + j;
        int col = bn + wc * 64 + n * 16 + fr;
        if (col < Nact) {
          float v = acc[m][n][j];
          if (bias) v += bias[col];
          if (resid) v += resid[(size_t)row * ldr + col];
          if (act == 1) v = (v > 20.f) ? v : log1pf(__expf(v));  // softplus
          C[(size_t)row * ldc + col] = v;
          if (aux && col < auxN) aux[(size_t)row * auxN + col] = f2bf(v);
        }
      }
    }
  }
}

// ---------------- causal depthwise conv (K=4) + silu; fp32 + bf16 outputs ----------------
__global__ __launch_bounds__(256)
void conv_silu_kernel(const float* __restrict__ xp, const float* __restrict__ w,
                      const float* __restrict__ cb, float* __restrict__ xc,
                      u16* __restrict__ xcb) {
  int idx = blockIdx.x * 256 + threadIdx.x;  // over CB*CS*CDI = 4M
  int d = idx & (CDI - 1);
  int t = (idx >> 11) & (CS - 1);
  int b = idx >> 21;
  const float* col = xp + (size_t)b * CS * CDI + d;
  float acc = cb[d];
#pragma unroll
  for (int k = 0; k < 4; ++k) {
    int tt = t - 3 + k;
    if (tt >= 0) acc = fmaf(col[(size_t)tt * CDI], w[d * 4 + k], acc);
  }
  float v = acc * (1.f / (1.f + __expf(-acc)));
  xc[idx] = v;
  xcb[idx] = f2bf(v);
}

// ---------------- selective scan, 3-phase chunked ----------------
__global__ __launch_bounds__(256)
void scan_phase1(const float* __restrict__ dt, const float* __restrict__ xc,
                 const float* __restrict__ dbc, const float* __restrict__ A_log,
                 float* __restrict__ P, float* __restrict__ Q) {
  int gid = blockIdx.x * 256 + threadIdx.x;
  int n = gid & 15;
  int d = (gid >> 4) & (CDI - 1);
  int c = (gid >> 15) & (CNCH - 1);
  int b = gid >> 19;
  float acoef = -__expf(A_log[d * CN + n]);
  float Pv = 1.f, Qv = 0.f;
  size_t rowbase = (size_t)b * CS + c * CCL;
  for (int i = 0; i < CCL; ++i) {
    size_t r = rowbase + i;
    float dtv = dt[r * CDI + d];
    float xcv = xc[r * CDI + d];
    float bsv = dbc[r * 96 + 64 + n];
    float a = __expf(dtv * acoef);
    Pv *= a;
    Qv = fmaf(a, Qv, dtv * xcv * bsv);
  }
  size_t o = (((size_t)b * CNCH + c) * CDI + d) * CN + n;
  P[o] = Pv; Q[o] = Qv;
}

__global__ __launch_bounds__(256)
void scan_phase2(const float* __restrict__ P, const float* __restrict__ Q,
                 float* __restrict__ HS) {
  int gid = blockIdx.x * 256 + threadIdx.x;  // CB*CDI*CN = 65536
  int n = gid & 15;
  int d = (gid >> 4) & (CDI - 1);
  int b = gid >> 15;
  float h = 0.f;
  for (int c = 0; c < CNCH; ++c) {
    size_t o = (((size_t)b * CNCH + c) * CDI + d) * CN + n;
    float p = P[o], q = Q[o];
    HS[o] = h;
    h = fmaf(p, h, q);
  }
}

__global__ __launch_bounds__(256)
void scan_phase3(const float* __restrict__ dt, const float* __restrict__ xc,
                 const float* __restrict__ dbc, const float* __restrict__ A_log,
                 const float* __restrict__ HS, const float* __restrict__ z,
                 const float* __restrict__ Dskip, u16* __restrict__ y2b) {
  int gid = blockIdx.x * 256 + threadIdx.x;
  int n = gid & 15;
  int d = (gid >> 4) & (CDI - 1);
  int c = (gid >> 15) & (CNCH - 1);
  int b = gid >> 19;
  float acoef = -__expf(A_log[d * CN + n]);
  size_t o = (((size_t)b * CNCH + c) * CDI + d) * CN + n;
  float h = HS[o];
  float dsk = Dskip[d];
  size_t rowbase = (size_t)b * CS + c * CCL;
  for (int i = 0; i < CCL; ++i) {
    size_t r = rowbase + i;
    float dtv = dt[r * CDI + d];
    float xcv = xc[r * CDI + d];
    float bsv = dbc[r * 96 + 64 + n];
    float csv = dbc[r * 96 + 80 + n];
    float a = __expf(dtv * acoef);
    h = fmaf(a, h, dtv * xcv * bsv);
    float yv = h * csv;
    yv += __shfl_xor(yv, 1);
    yv += __shfl_xor(yv, 2);
    yv += __shfl_xor(yv, 4);
    yv += __shfl_xor(yv, 8);
    if (n == 0) {
      float zv = z[r * CDI + d];
      float sz = zv * (1.f / (1.f + __expf(-zv)));
      y2b[r * CDI + d] = f2bf((yv + xcv * dsk) * sz);
    }
  }
}

// ---------------- soliton stencil -> bf16 ----------------
__global__ __launch_bounds__(256)
void soliton_kernel(const float* __restrict__ uu, const float* __restrict__ gates,
                    const float* __restrict__ alpha, u16* __restrict__ sol) {
  int idx = blockIdx.x * 256 + threadIdx.x;  // CB*CS*CD = 2M
  int d = idx & (CD - 1);
  int t = (idx >> 10) & (CS - 1);
  int b = idx >> 20;
  int h = d >> 6;
  const float* base = uu + (size_t)b * CS * CD + d;
  int tm2 = max(t - 2, 0), tm1 = max(t - 1, 0);
  int tp1 = min(t + 1, CS - 1), tp2 = min(t + 2, CS - 1);
  float um2 = base[(size_t)tm2 * CD];
  float um1 = base[(size_t)tm1 * CD];
  float u0  = base[(size_t)t   * CD];
  float up1 = base[(size_t)tp1 * CD];
  float up2 = base[(size_t)tp2 * CD];
  float ux   = (up1 - um1) * 0.5f;
  float uxx  = up1 - 2.f * u0 + um1;
  float uxxx = (up2 - 2.f * up1 + 2.f * um1 - um2) * 0.5f;
  float sg = sinf(u0);
  float kdv = -6.f * u0 * ux - uxxx;
  float hj = (1.f + alpha[h] * u0) * uxx;
  float du = gates[h * 3 + 0] * sg + gates[h * 3 + 1] * kdv + gates[h * 3 + 2] * hj;
  sol[idx] = f2bf(0.1f * du);
}

extern "C" void kernel_launch(void* const* d_in, const int* in_sizes, int n_in,
                              void* d_out, int out_size, void* d_ws, size_t ws_size,
                              hipStream_t stream) {
  const float* x      = (const float*)d_in[0];
  const float* ln1_g  = (const float*)d_in[1];
  const float* ln1_b  = (const float*)d_in[2];
  const float* W_in   = (const float*)d_in[3];
  const float* b_in   = (const float*)d_in[4];
  const float* conv_w = (const float*)d_in[5];
  const float* conv_b = (const float*)d_in[6];
  const float* W_xp   = (const float*)d_in[7];
  const float* W_dt   = (const float*)d_in[8];
  const float* b_dt   = (const float*)d_in[9];
  const float* A_log  = (const float*)d_in[10];
  const float* D_skip = (const float*)d_in[11];
  const float* W_out  = (const float*)d_in[12];
  const float* b_out  = (const float*)d_in[13];
  const float* ln2_g  = (const float*)d_in[14];
  const float* ln2_b  = (const float*)d_in[15];
  const float* W_si   = (const float*)d_in[16];
  const float* b_si   = (const float*)d_in[17];
  const float* gates  = (const float*)d_in[18];
  const float* alpha  = (const float*)d_in[19];
  const float* W_so   = (const float*)d_in[20];
  const float* b_so   = (const float*)d_in[21];
  float* out = (float*)d_out;

  float* ws = (float*)d_ws;
  size_t off = 0;
  auto alloc = [&](size_t nwords) { float* p = ws + off; off += nwords; return p; };
  const size_t BS = (size_t)CB * CS;  // 2048 rows
  const size_t M1 = 1024 * 1024;

  float* WtinF = alloc(2 * M1);            // Wt_in: 4096x1024 bf16 (4M elems)
  u16*   Wt_in = (u16*)WtinF;
  float* Pb = WtinF;                        // alias (Wt_in dead after gemm1)
  float* Qb = WtinF + M1;
  u16* Wt_xp  = (u16*)alloc(128 * 1024);   // 128x2048 bf16 (padded 96->128)
  u16* Wt_dt  = (u16*)alloc(64 * 1024);    // 2048x64 bf16
  u16* Wt_out = (u16*)alloc(M1);           // 1024x2048 bf16
  u16* Wt_si  = (u16*)alloc(M1 / 2);       // 1024x1024 bf16
  u16* Wt_so  = (u16*)alloc(M1 / 2);
  u16* u_bf   = (u16*)alloc(M1);           // 2048x1024 bf16; alias sol_bf
  u16* sol_bf = u_bf;
  float* xp   = alloc(4 * M1);             // alias dt (xp dead after conv)
  float* dt   = xp;
  float* z    = alloc(4 * M1);
  float* xc   = alloc(4 * M1);             // alias uu
  float* uu   = xc;
  u16* xc_bf  = (u16*)alloc(2 * M1);       // 2048x2048 bf16
  float* dbc  = alloc(BS * 96);
  u16* dtr_bf = (u16*)alloc(64 * 1024);    // 2048x64 bf16
  float* HS   = alloc(M1);
  u16* y2_bf  = (u16*)alloc(2 * M1);       // 2048x2048 bf16

  dim3 blk(256);

  // 0. weight transpose-converts (fp32 [K][N] -> bf16 [Npad][K])
  transpose_bf16_kernel<<<dim3(128, 32), blk, 0, stream>>>(W_in, Wt_in, 1024, 4096, 4096);
  transpose_bf16_kernel<<<dim3(4, 64), blk, 0, stream>>>(W_xp, Wt_xp, 2048, 96, 128);
  transpose_bf16_kernel<<<dim3(64, 2), blk, 0, stream>>>(W_dt, Wt_dt, 64, 2048, 2048);
  transpose_bf16_kernel<<<dim3(32, 64), blk, 0, stream>>>(W_out, Wt_out, 2048, 1024, 1024);
  transpose_bf16_kernel<<<dim3(32, 32), blk, 0, stream>>>(W_si, Wt_si, 1024, 1024, 1024);
  transpose_bf16_kernel<<<dim3(32, 32), blk, 0, stream>>>(W_so, Wt_so, 1024, 1024, 1024);

  // 1. u = LN1(x) -> bf16
  ln_kernel<<<BS, blk, 0, stream>>>(x, ln1_g, ln1_b, u_bf);
  // 2-3. xp | z = u @ W_in + b_in (column halves)
  gemm_bf16_kernel<<<dim3(16, 16), blk, 0, stream>>>(u_bf, 1024, Wt_in, 1024, b_in, nullptr, 0,
                                                     xp, CDI, nullptr, 0, 2048, 1024, 0);
  gemm_bf16_kernel<<<dim3(16, 16), blk, 0, stream>>>(u_bf, 1024, Wt_in + 2048 * 1024, 1024,
                                                     b_in + CDI, nullptr, 0,
                                                     z, CDI, nullptr, 0, 2048, 1024, 0);
  // 4. xc = silu(conv(xp) + conv_b)  (fp32 + bf16)
  conv_silu_kernel<<<(BS * CDI) / 256, blk, 0, stream>>>(xp, conv_w, conv_b, xc, xc_bf);
  // 5. dbc = xc @ W_xp (N=96, padded tile); aux writes dtr cols 0-63 as bf16
  gemm_bf16_kernel<<<dim3(1, 16), blk, 0, stream>>>(xc_bf, 2048, Wt_xp, 2048, nullptr, nullptr, 0,
                                                    dbc, 96, dtr_bf, 64, 96, 2048, 0);
  // 6. dt = softplus(dtr @ W_dt + b_dt)  (K=64); dt aliases xp
  gemm_bf16_kernel<<<dim3(16, 16), blk, 0, stream>>>(dtr_bf, 64, Wt_dt, 64, b_dt, nullptr, 0,
                                                     dt, CDI, nullptr, 0, 2048, 64, 0 + 1);
  // 7-9. chunked selective scan; phase3 fuses y2 = (y + xc*D_skip)*silu(z) -> bf16
  scan_phase1<<<(CB * CNCH * CDI * CN) / 256, blk, 0, stream>>>(dt, xc, dbc, A_log, Pb, Qb);
  scan_phase2<<<(CB * CDI * CN) / 256, blk, 0, stream>>>(Pb, Qb, HS);
  scan_phase3<<<(CB * CNCH * CDI * CN) / 256, blk, 0, stream>>>(dt, xc, dbc, A_log, HS, z, D_skip, y2_bf);
  // 10. x1 = x + y2 @ W_out + b_out -> d_out
  gemm_bf16_kernel<<<dim3(8, 16), blk, 0, stream>>>(y2_bf, 2048, Wt_out, 2048, b_out, x, 1024,
                                                    out, CD, nullptr, 0, 1024, 2048, 0);
  // 11. v = LN2(x1) -> bf16 (reuse u_bf)
  ln_kernel<<<BS, blk, 0, stream>>>(out, ln2_g, ln2_b, u_bf);
  // 12. uu = v @ W_si + b_si  (fp32, aliases xc)
  gemm_bf16_kernel<<<dim3(8, 16), blk, 0, stream>>>(u_bf, 1024, Wt_si, 1024, b_si, nullptr, 0,
                                                    uu, CD, nullptr, 0, 1024, 1024, 0);
  // 13. sol = 0.1 * du(uu) -> bf16 (aliases u_bf, dead after gemm5)
  soliton_kernel<<<(BS * CD) / 256, blk, 0, stream>>>(uu, gates, alpha, sol_bf);
  // 14. out = x1 + sol @ W_so + b_so
  gemm_bf16_kernel<<<dim3(8, 16), blk, 0, stream>>>(sol_bf, 1024, Wt_so, 1024, b_so, out, 1024,
                                                    out, CD, nullptr, 0, 1024, 1024, 0);
}

// Round 3
// 339.446 us; speedup vs baseline: 4.2168x; 1.4355x over previous
//
#include <hip/hip_runtime.h>
#include <hip/hip_bf16.h>
#include <math.h>

typedef unsigned short u16;
typedef unsigned int u32;
typedef __attribute__((ext_vector_type(8))) short short8;
typedef __attribute__((ext_vector_type(4))) float f32x4;

constexpr int CB = 2;
constexpr int CS = 1024;
constexpr int CD = 1024;
constexpr int CDI = 2048;
constexpr int CNC2 = 64;   // scan chunks
constexpr int CL2 = 16;    // chunk length = CS / CNC2

__device__ inline u16 f2bf(float v) {
  __hip_bfloat16 h = __float2bfloat16(v);
  return *reinterpret_cast<u16*>(&h);
}
__device__ inline float bf2f(u16 v) {
  return __uint_as_float(((u32)v) << 16);
}

__device__ inline void gload16(const void* g, void* l) {
  __builtin_amdgcn_global_load_lds((const __attribute__((address_space(1))) void*)g,
                                   (__attribute__((address_space(3))) void*)l, 16, 0, 0);
}

// ---------------- transpose + fp32->bf16 convert: in[K][N] -> out[Npad][K] ----------------
__global__ __launch_bounds__(256)
void transpose_bf16_kernel(const float* __restrict__ in, u16* __restrict__ out,
                           int K, int N, int Npad) {
  __shared__ float tile[32][33];
  int n0 = blockIdx.x * 32, k0 = blockIdx.y * 32;
  int tx = threadIdx.x & 31, ty = threadIdx.x >> 5;  // 32 x 8
#pragma unroll
  for (int i = 0; i < 4; ++i) {
    int k = k0 + ty + i * 8, n = n0 + tx;
    tile[ty + i * 8][tx] = (n < N) ? in[(size_t)k * N + n] : 0.f;
  }
  __syncthreads();
#pragma unroll
  for (int i = 0; i < 4; ++i) {
    int n = n0 + ty + i * 8, k = k0 + tx;
    out[(size_t)n * K + k] = f2bf(tile[tx][ty + i * 8]);
  }
}

// ---------------- LayerNorm -> bf16 ----------------
__global__ __launch_bounds__(256)
void ln_kernel(const float* __restrict__ x, const float* __restrict__ g,
               const float* __restrict__ bb, u16* __restrict__ outb) {
  int row = blockIdx.x;
  const float4* xr = (const float4*)(x + (size_t)row * CD);
  float4 v = xr[threadIdx.x];
  float s = v.x + v.y + v.z + v.w;
  float ss = v.x * v.x + v.y * v.y + v.z * v.z + v.w * v.w;
#pragma unroll
  for (int o = 1; o < 64; o <<= 1) { s += __shfl_xor(s, o); ss += __shfl_xor(ss, o); }
  __shared__ float sb[4], ssb[4];
  int wid = threadIdx.x >> 6;
  if ((threadIdx.x & 63) == 0) { sb[wid] = s; ssb[wid] = ss; }
  __syncthreads();
  s = sb[0] + sb[1] + sb[2] + sb[3];
  ss = ssb[0] + ssb[1] + ssb[2] + ssb[3];
  float mu = s * (1.f / CD);
  float var = ss * (1.f / CD) - mu * mu;
  float rstd = rsqrtf(var + 1e-5f);
  float4 gv = ((const float4*)g)[threadIdx.x];
  float4 bv = ((const float4*)bb)[threadIdx.x];
  ushort4 o;
  o.x = f2bf((v.x - mu) * rstd * gv.x + bv.x);
  o.y = f2bf((v.y - mu) * rstd * gv.y + bv.y);
  o.z = f2bf((v.z - mu) * rstd * gv.z + bv.z);
  o.w = f2bf((v.w - mu) * rstd * gv.w + bv.w);
  ((ushort4*)(outb + (size_t)row * CD))[threadIdx.x] = o;
}

// ---------------- bf16 MFMA GEMM: C = act(A @ Bt^T + bias + resid) ----------------
// Tile 128x128, BK=64, 4 waves each owning a 64x64 sub-tile. Optional split-K over
// blockIdx.z (atomicAdd path; bias/resid/act/aux must be off in that mode).
__global__ __launch_bounds__(256)
void gemm_bf16_kernel(const u16* __restrict__ A, int lda,
                      const u16* __restrict__ Bt, int ldb,
                      const float* __restrict__ bias,
                      const float* __restrict__ resid, int ldr,
                      float* __restrict__ C, int ldc,
                      u16* __restrict__ aux, int auxN,
                      int Nact, int K, int act) {
  __shared__ __align__(16) u16 As[128 * 64];
  __shared__ __align__(16) u16 Bs[128 * 64];
  const int tid = threadIdx.x, lane = tid & 63, wid = tid >> 6;
  const int wr = wid >> 1, wc = wid & 1;
  const int bm = blockIdx.y * 128, bn = blockIdx.x * 128;
  const int ksegs = gridDim.z;
  const int kper = K / ksegs;
  const int kbeg = blockIdx.z * kper, kend = kbeg + kper;
  f32x4 acc[4][4] = {};

  for (int k0 = kbeg; k0 < kend; k0 += 64) {
    __syncthreads();  // protect LDS before overwrite
#pragma unroll
    for (int j = 0; j < 4; ++j) {
      int cbase = j * 256 + wid * 64;     // wave-uniform dest chunk base
      int c = cbase + lane;               // this lane's dest chunk
      int row = c >> 3;                   // 8 chunks (128B) per row
      int kc = (c & 7) ^ (row & 7);       // inverse-swizzled source chunk
      gload16(A + (size_t)(bm + row) * lda + k0 + kc * 8, As + cbase * 8);
      gload16(Bt + (size_t)(bn + row) * ldb + k0 + kc * 8, Bs + cbase * 8);
    }
    __syncthreads();  // compiler drains vmcnt(0) before barrier
#pragma unroll
    for (int ks = 0; ks < 64; ks += 32) {
      short8 af[4], bfr[4];
#pragma unroll
      for (int m = 0; m < 4; ++m) {
        int r = wr * 64 + m * 16 + (lane & 15);
        int ch = (lane >> 4) + (ks >> 3);
        af[m] = *(const short8*)&As[r * 64 + ((ch ^ (r & 7)) << 3)];
      }
#pragma unroll
      for (int n = 0; n < 4; ++n) {
        int r = wc * 64 + n * 16 + (lane & 15);
        int ch = (lane >> 4) + (ks >> 3);
        bfr[n] = *(const short8*)&Bs[r * 64 + ((ch ^ (r & 7)) << 3)];
      }
#pragma unroll
      for (int m = 0; m < 4; ++m)
#pragma unroll
        for (int n = 0; n < 4; ++n)
          acc[m][n] = __builtin_amdgcn_mfma_f32_16x16x32_bf16(af[m], bfr[n], acc[m][n], 0, 0, 0);
    }
  }

  const int fr = lane & 15, fq = lane >> 4;
#pragma unroll
  for (int m = 0; m < 4; ++m) {
#pragma unroll
    for (int n = 0; n < 4; ++n) {
#pragma unroll
      for (int j = 0; j < 4; ++j) {
        int row = bm + wr * 64 + m * 16 + fq * 4 + j;
        int col = bn + wc * 64 + n * 16 + fr;
        if (col < Nact) {
          float v = acc[m][n][j];
          if (ksegs == 1) {
            if (bias) v += bias[col];
            if (resid) v += resid[(size_t)row * ldr + col];
            if (act == 1) v = (v > 20.f) ? v : log1pf(__expf(v));  // softplus
            if (C) C[(size_t)row * ldc + col] = v;
            if (aux && col < auxN) aux[(size_t)row * auxN + col] = f2bf(v);
          } else {
            atomicAdd(&C[(size_t)row * ldc + col], v);
          }
        }
      }
    }
  }
}

// ---------------- causal depthwise conv (K=4) + silu -> bf16 ----------------
// input xz [B][S][4096], cols 0..2047 are xp
__global__ __launch_bounds__(256)
void conv_silu_kernel(const float* __restrict__ xz, const float* __restrict__ w,
                      const float* __restrict__ cb, u16* __restrict__ xcb) {
  int idx = blockIdx.x * 256 + threadIdx.x;  // over CB*CS*CDI = 4M
  int d = idx & (CDI - 1);
  int t = (idx >> 11) & (CS - 1);
  int b = idx >> 21;
  const float* col = xz + (size_t)b * CS * 4096 + d;
  float acc = cb[d];
#pragma unroll
  for (int k = 0; k < 4; ++k) {
    int tt = t - 3 + k;
    if (tt >= 0) acc = fmaf(col[(size_t)tt * 4096], w[d * 4 + k], acc);
  }
  float v = acc * (1.f / (1.f + __expf(-acc)));
  xcb[idx] = f2bf(v);
}

// ---------------- dbc[:,0:64] -> bf16 ----------------
__global__ __launch_bounds__(256)
void dtr_convert_kernel(const float* __restrict__ dbc, u16* __restrict__ dtrb) {
  int idx = blockIdx.x * 256 + threadIdx.x;  // 2048*64
  int r = idx >> 6, k = idx & 63;
  dtrb[idx] = f2bf(dbc[r * 96 + k]);
}

// ---------------- selective scan: thread per (b,chunk,d), N=16 in registers ----------------
__global__ __launch_bounds__(256)
void scan1_kernel(const float* __restrict__ dt, const u16* __restrict__ xcb,
                  const float* __restrict__ dbc, const float* __restrict__ A_log,
                  u16* __restrict__ P, u16* __restrict__ Q) {
  int gid = blockIdx.x * 256 + threadIdx.x;  // CB*CNC2*CDI = 262144
  int d = gid & (CDI - 1);
  int c = (gid >> 11) & (CNC2 - 1);
  int b = gid >> 17;
  float acoef[16];
#pragma unroll
  for (int j = 0; j < 4; ++j) {
    float4 al = ((const float4*)(A_log + d * 16))[j];
    acoef[j * 4 + 0] = -__expf(al.x);
    acoef[j * 4 + 1] = -__expf(al.y);
    acoef[j * 4 + 2] = -__expf(al.z);
    acoef[j * 4 + 3] = -__expf(al.w);
  }
  float Pv[16], Qv[16];
#pragma unroll
  for (int n = 0; n < 16; ++n) { Pv[n] = 1.f; Qv[n] = 0.f; }
  size_t rowbase = (size_t)b * CS + (size_t)c * CL2;
  for (int i = 0; i < CL2; ++i) {
    size_t r = rowbase + i;
    float dtv = dt[r * CDI + d];
    float xcv = bf2f(xcb[r * CDI + d]);
    float dx = dtv * xcv;
    const float4* bs4 = (const float4*)(dbc + r * 96 + 64);
    float bs[16];
#pragma unroll
    for (int j = 0; j < 4; ++j) {
      float4 t4 = bs4[j];
      bs[j * 4 + 0] = t4.x; bs[j * 4 + 1] = t4.y; bs[j * 4 + 2] = t4.z; bs[j * 4 + 3] = t4.w;
    }
#pragma unroll
    for (int n = 0; n < 16; ++n) {
      float a = __expf(dtv * acoef[n]);
      Pv[n] *= a;
      Qv[n] = fmaf(a, Qv[n], dx * bs[n]);
    }
  }
  size_t o = (((size_t)b * CNC2 + c) * CDI + d) * 16;
  u16 pb[16], qb[16];
#pragma unroll
  for (int n = 0; n < 16; ++n) { pb[n] = f2bf(Pv[n]); qb[n] = f2bf(Qv[n]); }
#pragma unroll
  for (int j = 0; j < 2; ++j) {
    *(short8*)(P + o + j * 8) = *(short8*)(pb + j * 8);
    *(short8*)(Q + o + j * 8) = *(short8*)(qb + j * 8);
  }
}

// combine chunk summaries; rewrites Q in place with chunk-START state h0
__global__ __launch_bounds__(256)
void scan2_kernel(const u16* __restrict__ P, u16* __restrict__ Q) {
  int gid = blockIdx.x * 256 + threadIdx.x;  // CB*CDI*16 = 65536
  int n = gid & 15;
  int d = (gid >> 4) & (CDI - 1);
  int b = gid >> 15;
  float h = 0.f;
  for (int c = 0; c < CNC2; ++c) {
    size_t o = (((size_t)b * CNC2 + c) * CDI + d) * 16 + n;
    float p = bf2f(P[o]), q = bf2f(Q[o]);
    Q[o] = f2bf(h);
    h = fmaf(p, h, q);
  }
}

__global__ __launch_bounds__(256)
void scan3_kernel(const float* __restrict__ dt, const u16* __restrict__ xcb,
                  const float* __restrict__ dbc, const float* __restrict__ A_log,
                  const u16* __restrict__ Q, const float* __restrict__ xz,
                  const float* __restrict__ Dskip, u16* __restrict__ y2b) {
  int gid = blockIdx.x * 256 + threadIdx.x;  // 262144
  int d = gid & (CDI - 1);
  int c = (gid >> 11) & (CNC2 - 1);
  int b = gid >> 17;
  float acoef[16];
#pragma unroll
  for (int j = 0; j < 4; ++j) {
    float4 al = ((const float4*)(A_log + d * 16))[j];
    acoef[j * 4 + 0] = -__expf(al.x);
    acoef[j * 4 + 1] = -__expf(al.y);
    acoef[j * 4 + 2] = -__expf(al.z);
    acoef[j * 4 + 3] = -__expf(al.w);
  }
  float h[16];
  size_t o = (((size_t)b * CNC2 + c) * CDI + d) * 16;
#pragma unroll
  for (int j = 0; j < 2; ++j) {
    short8 q8 = *(const short8*)(Q + o + j * 8);
#pragma unroll
    for (int n = 0; n < 8; ++n) h[j * 8 + n] = bf2f((u16)q8[n]);
  }
  float dsk = Dskip[d];
  size_t rowbase = (size_t)b * CS + (size_t)c * CL2;
  for (int i = 0; i < CL2; ++i) {
    size_t r = rowbase + i;
    float dtv = dt[r * CDI + d];
    float xcv = bf2f(xcb[r * CDI + d]);
    float zv = xz[r * 4096 + 2048 + d];
    float dx = dtv * xcv;
    const float4* bc4 = (const float4*)(dbc + r * 96 + 64);
    float bs[16], cs[16];
#pragma unroll
    for (int j = 0; j < 4; ++j) {
      float4 t4 = bc4[j];
      bs[j * 4 + 0] = t4.x; bs[j * 4 + 1] = t4.y; bs[j * 4 + 2] = t4.z; bs[j * 4 + 3] = t4.w;
      float4 u4 = bc4[4 + j];
      cs[j * 4 + 0] = u4.x; cs[j * 4 + 1] = u4.y; cs[j * 4 + 2] = u4.z; cs[j * 4 + 3] = u4.w;
    }
    float y = 0.f;
#pragma unroll
    for (int n = 0; n < 16; ++n) {
      float a = __expf(dtv * acoef[n]);
      h[n] = fmaf(a, h[n], dx * bs[n]);
      y = fmaf(h[n], cs[n], y);
    }
    float sz = zv * (1.f / (1.f + __expf(-zv)));
    y2b[r * CDI + d] = f2bf((y + xcv * dsk) * sz);
  }
}

// ---------------- soliton stencil -> bf16 ----------------
__global__ __launch_bounds__(256)
void soliton_kernel(const float* __restrict__ uu, const float* __restrict__ gates,
                    const float* __restrict__ alpha, u16* __restrict__ sol) {
  int idx = blockIdx.x * 256 + threadIdx.x;  // CB*CS*CD = 2M
  int d = idx & (CD - 1);
  int t = (idx >> 10) & (CS - 1);
  int b = idx >> 20;
  int h = d >> 6;
  const float* base = uu + (size_t)b * CS * CD + d;
  int tm2 = max(t - 2, 0), tm1 = max(t - 1, 0);
  int tp1 = min(t + 1, CS - 1), tp2 = min(t + 2, CS - 1);
  float um2 = base[(size_t)tm2 * CD];
  float um1 = base[(size_t)tm1 * CD];
  float u0  = base[(size_t)t   * CD];
  float up1 = base[(size_t)tp1 * CD];
  float up2 = base[(size_t)tp2 * CD];
  float ux   = (up1 - um1) * 0.5f;
  float uxx  = up1 - 2.f * u0 + um1;
  float uxxx = (up2 - 2.f * up1 + 2.f * um1 - um2) * 0.5f;
  float sg = sinf(u0);
  float kdv = -6.f * u0 * ux - uxxx;
  float hj = (1.f + alpha[h] * u0) * uxx;
  float du = gates[h * 3 + 0] * sg + gates[h * 3 + 1] * kdv + gates[h * 3 + 2] * hj;
  sol[idx] = f2bf(0.1f * du);
}

extern "C" void kernel_launch(void* const* d_in, const int* in_sizes, int n_in,
                              void* d_out, int out_size, void* d_ws, size_t ws_size,
                              hipStream_t stream) {
  const float* x      = (const float*)d_in[0];
  const float* ln1_g  = (const float*)d_in[1];
  const float* ln1_b  = (const float*)d_in[2];
  const float* W_in   = (const float*)d_in[3];
  const float* b_in   = (const float*)d_in[4];
  const float* conv_w = (const float*)d_in[5];
  const float* conv_b = (const float*)d_in[6];
  const float* W_xp   = (const float*)d_in[7];
  const float* W_dt   = (const float*)d_in[8];
  const float* b_dt   = (const float*)d_in[9];
  const float* A_log  = (const float*)d_in[10];
  const float* D_skip = (const float*)d_in[11];
  const float* W_out  = (const float*)d_in[12];
  const float* b_out  = (const float*)d_in[13];
  const float* ln2_g  = (const float*)d_in[14];
  const float* ln2_b  = (const float*)d_in[15];
  const float* W_si   = (const float*)d_in[16];
  const float* b_si   = (const float*)d_in[17];
  const float* gates  = (const float*)d_in[18];
  const float* alpha  = (const float*)d_in[19];
  const float* W_so   = (const float*)d_in[20];
  const float* b_so   = (const float*)d_in[21];
  float* out = (float*)d_out;

  float* ws = (float*)d_ws;
  size_t off = 0;
  auto alloc = [&](size_t nwords) { float* p = ws + off; off += nwords; return p; };
  const size_t BS = (size_t)CB * CS;  // 2048 rows
  const size_t M1 = 1024 * 1024;

  u16* Wt_in  = (u16*)alloc(2 * M1);       // 4096x1024 bf16
  u16* Wt_xp  = (u16*)alloc(128 * 1024);   // 128x2048 bf16 (padded 96->128)
  u16* Wt_dt  = (u16*)alloc(64 * 1024);    // 2048x64 bf16
  u16* Wt_out = (u16*)alloc(M1);           // 1024x2048 bf16
  u16* Wt_si  = (u16*)alloc(M1 / 2);       // 1024x1024 bf16
  u16* Wt_so  = (u16*)alloc(M1 / 2);
  u16* u_bf   = (u16*)alloc(M1);           // 2048x1024 bf16; alias sol_bf
  u16* sol_bf = u_bf;
  float* xz   = alloc(8 * M1);             // 2048x4096 fp32 (xp | z)
  float* dt   = alloc(4 * M1);             // 2048x2048 fp32
  u16* xc_bf  = (u16*)alloc(2 * M1);       // 2048x2048 bf16
  float* dbc  = alloc(BS * 96);
  u16* dtr_bf = (u16*)alloc(64 * 1024);    // 2048x64 bf16
  u16* Pb     = (u16*)alloc(2 * M1);       // 2*64*2048*16 bf16 (8MB)
  u16* Qb     = (u16*)alloc(2 * M1);       // same; becomes h0 after scan2
  u16* y2_bf  = (u16*)alloc(2 * M1);       // 2048x2048 bf16
  float* uu   = (float*)Pb;                // 2048x1024 fp32 (8MB), Pb dead after scan2

  dim3 blk(256);

  // 0. weight transpose-converts (fp32 [K][N] -> bf16 [Npad][K])
  transpose_bf16_kernel<<<dim3(128, 32), blk, 0, stream>>>(W_in, Wt_in, 1024, 4096, 4096);
  transpose_bf16_kernel<<<dim3(4, 64), blk, 0, stream>>>(W_xp, Wt_xp, 2048, 96, 128);
  transpose_bf16_kernel<<<dim3(64, 2), blk, 0, stream>>>(W_dt, Wt_dt, 64, 2048, 2048);
  transpose_bf16_kernel<<<dim3(32, 64), blk, 0, stream>>>(W_out, Wt_out, 2048, 1024, 1024);
  transpose_bf16_kernel<<<dim3(32, 32), blk, 0, stream>>>(W_si, Wt_si, 1024, 1024, 1024);
  transpose_bf16_kernel<<<dim3(32, 32), blk, 0, stream>>>(W_so, Wt_so, 1024, 1024, 1024);

  // 1. u = LN1(x) -> bf16
  ln_kernel<<<BS, blk, 0, stream>>>(x, ln1_g, ln1_b, u_bf);
  // 2. xz = u @ W_in + b_in  (both halves in one dispatch, N=4096)
  gemm_bf16_kernel<<<dim3(32, 16), blk, 0, stream>>>(u_bf, 1024, Wt_in, 1024, b_in, nullptr, 0,
                                                     xz, 4096, nullptr, 0, 4096, 1024, 0);
  // 3. xc = silu(conv(xp) + conv_b) -> bf16
  conv_silu_kernel<<<(BS * CDI) / 256, blk, 0, stream>>>(xz, conv_w, conv_b, xc_bf);
  // 4. dbc = xc @ W_xp (N=96), split-K=8 with atomicAdd
  hipMemsetAsync(dbc, 0, BS * 96 * sizeof(float), stream);
  gemm_bf16_kernel<<<dim3(1, 16, 8), blk, 0, stream>>>(xc_bf, 2048, Wt_xp, 2048, nullptr, nullptr, 0,
                                                       dbc, 96, nullptr, 0, 96, 2048, 0);
  dtr_convert_kernel<<<(BS * 64) / 256, blk, 0, stream>>>(dbc, dtr_bf);
  // 5. dt = softplus(dtr @ W_dt + b_dt)
  gemm_bf16_kernel<<<dim3(16, 16), blk, 0, stream>>>(dtr_bf, 64, Wt_dt, 64, b_dt, nullptr, 0,
                                                     dt, CDI, nullptr, 0, 2048, 64, 1);
  // 6-8. chunked selective scan (N in registers)
  scan1_kernel<<<(CB * CNC2 * CDI) / 256, blk, 0, stream>>>(dt, xc_bf, dbc, A_log, Pb, Qb);
  scan2_kernel<<<(CB * CDI * 16) / 256, blk, 0, stream>>>(Pb, Qb);
  scan3_kernel<<<(CB * CNC2 * CDI) / 256, blk, 0, stream>>>(dt, xc_bf, dbc, A_log, Qb, xz, D_skip, y2_bf);
  // 9. x1 = x + y2 @ W_out + b_out -> d_out
  gemm_bf16_kernel<<<dim3(8, 16), blk, 0, stream>>>(y2_bf, 2048, Wt_out, 2048, b_out, x, 1024,
                                                    out, CD, nullptr, 0, 1024, 2048, 0);
  // 10. v = LN2(x1) -> bf16
  ln_kernel<<<BS, blk, 0, stream>>>(out, ln2_g, ln2_b, u_bf);
  // 11. uu = v @ W_si + b_si (fp32; aliases Pb which is dead)
  gemm_bf16_kernel<<<dim3(8, 16), blk, 0, stream>>>(u_bf, 1024, Wt_si, 1024, b_si, nullptr, 0,
                                                    uu, CD, nullptr, 0, 1024, 1024, 0);
  // 12. sol = 0.1 * du(uu) -> bf16 (aliases u_bf; gemm 11 already consumed it)
  soliton_kernel<<<(BS * CD) / 256, blk, 0, stream>>>(uu, gates, alpha, sol_bf);
  // 13. out = x1 + sol @ W_so + b_so
  gemm_bf16_kernel<<<dim3(8, 16), blk, 0, stream>>>(sol_bf, 1024, Wt_so, 1024, b_so, out, 1024,
                                                    out, CD, nullptr, 0, 1024, 1024, 0);
}

// Round 4
// 284.243 us; speedup vs baseline: 5.0357x; 1.1942x over previous
//
#include <hip/hip_runtime.h>
#include <hip/hip_bf16.h>
#include <math.h>

typedef unsigned short u16;
typedef unsigned int u32;
typedef __attribute__((ext_vector_type(8))) short short8;
typedef __attribute__((ext_vector_type(4))) float f32x4;

constexpr int CB = 2;
constexpr int CS = 1024;
constexpr int CD = 1024;
constexpr int CDI = 2048;
constexpr int CNC2 = 64;   // scan chunks
constexpr int CL2 = 16;    // chunk length = CS / CNC2

__device__ inline u16 f2bf(float v) {
  __hip_bfloat16 h = __float2bfloat16(v);
  return *reinterpret_cast<u16*>(&h);
}
__device__ inline float bf2f(u16 v) {
  return __uint_as_float(((u32)v) << 16);
}

__device__ inline void gload16(const void* g, void* l) {
  __builtin_amdgcn_global_load_lds((const __attribute__((address_space(1))) void*)g,
                                   (__attribute__((address_space(3))) void*)l, 16, 0, 0);
}

// ---------------- transpose + fp32->bf16 convert: in[K][N] -> out[Npad][K] ----------------
__global__ __launch_bounds__(256)
void transpose_bf16_kernel(const float* __restrict__ in, u16* __restrict__ out,
                           int K, int N, int Npad) {
  __shared__ float tile[32][33];
  int n0 = blockIdx.x * 32, k0 = blockIdx.y * 32;
  int tx = threadIdx.x & 31, ty = threadIdx.x >> 5;  // 32 x 8
#pragma unroll
  for (int i = 0; i < 4; ++i) {
    int k = k0 + ty + i * 8, n = n0 + tx;
    tile[ty + i * 8][tx] = (n < N) ? in[(size_t)k * N + n] : 0.f;
  }
  __syncthreads();
#pragma unroll
  for (int i = 0; i < 4; ++i) {
    int n = n0 + ty + i * 8, k = k0 + tx;
    out[(size_t)n * K + k] = f2bf(tile[tx][ty + i * 8]);
  }
}

// ---------------- LayerNorm -> bf16 ----------------
__global__ __launch_bounds__(256)
void ln_kernel(const float* __restrict__ x, const float* __restrict__ g,
               const float* __restrict__ bb, u16* __restrict__ outb) {
  int row = blockIdx.x;
  const float4* xr = (const float4*)(x + (size_t)row * CD);
  float4 v = xr[threadIdx.x];
  float s = v.x + v.y + v.z + v.w;
  float ss = v.x * v.x + v.y * v.y + v.z * v.z + v.w * v.w;
#pragma unroll
  for (int o = 1; o < 64; o <<= 1) { s += __shfl_xor(s, o); ss += __shfl_xor(ss, o); }
  __shared__ float sb[4], ssb[4];
  int wid = threadIdx.x >> 6;
  if ((threadIdx.x & 63) == 0) { sb[wid] = s; ssb[wid] = ss; }
  __syncthreads();
  s = sb[0] + sb[1] + sb[2] + sb[3];
  ss = ssb[0] + ssb[1] + ssb[2] + ssb[3];
  float mu = s * (1.f / CD);
  float var = ss * (1.f / CD) - mu * mu;
  float rstd = rsqrtf(var + 1e-5f);
  float4 gv = ((const float4*)g)[threadIdx.x];
  float4 bv = ((const float4*)bb)[threadIdx.x];
  ushort4 o;
  o.x = f2bf((v.x - mu) * rstd * gv.x + bv.x);
  o.y = f2bf((v.y - mu) * rstd * gv.y + bv.y);
  o.z = f2bf((v.z - mu) * rstd * gv.z + bv.z);
  o.w = f2bf((v.w - mu) * rstd * gv.w + bv.w);
  ((ushort4*)(outb + (size_t)row * CD))[threadIdx.x] = o;
}

// ---------------- bf16 MFMA GEMM, 2-phase double-buffered LDS ----------------
// C = act(A @ Bt^T + bias + resid). Tile 128xBN, BK=64, 4 waves (2x2).
// Prefetch next K-tile via global_load_lds BEFORE computing current tile; the
// __syncthreads at iter end (vmcnt0+barrier) overlaps load latency with compute.
// Split-K over blockIdx.z -> atomicAdd path (no bias/resid/act/aux).
template<int BN>
__global__ __launch_bounds__(256)
void gemm_bf16_kernel(const u16* __restrict__ A, int lda,
                      const u16* __restrict__ Bt, int ldb,
                      const float* __restrict__ bias,
                      const float* __restrict__ resid, int ldr,
                      float* __restrict__ C, int ldc,
                      u16* __restrict__ aux, int auxN,
                      int Nact, int K, int act) {
  constexpr int WN = BN / 32;            // n-frags per wave (BN=128 -> 4, 64 -> 2)
  __shared__ __align__(16) u16 As[2 * 128 * 64];
  __shared__ __align__(16) u16 Bs[2 * BN * 64];
  const int tid = threadIdx.x, lane = tid & 63, wid = tid >> 6;
  const int wr = wid >> 1, wc = wid & 1;
  // bijective XCD-chunked swizzle over the xy grid (nwg % 8 == 0 for all our grids)
  int nwg = gridDim.x * gridDim.y;
  int bid = blockIdx.y * gridDim.x + blockIdx.x;
  int swz = (bid & 7) * (nwg >> 3) + (bid >> 3);
  int bx = swz % gridDim.x, by = swz / gridDim.x;
  const int bm = by * 128, bn = bx * BN;
  const int ksegs = gridDim.z;
  const int kper = K / ksegs;
  const int kbeg = blockIdx.z * kper;
  const int nt = kper / 64;
  f32x4 acc[4][WN] = {};

  auto stage = [&](int t, int buf) {
    int k0 = kbeg + t * 64;
    u16* Ad = As + buf * (128 * 64);
    u16* Bd = Bs + buf * (BN * 64);
#pragma unroll
    for (int j = 0; j < 4; ++j) {
      int cbase = j * 256 + wid * 64;     // wave-uniform dest chunk base
      int c = cbase + lane;
      int row = c >> 3;
      int kc = (c & 7) ^ (row & 7);       // inverse-swizzled source chunk
      gload16(A + (size_t)(bm + row) * lda + k0 + kc * 8, Ad + cbase * 8);
    }
#pragma unroll
    for (int j = 0; j < BN / 32; ++j) {
      int cbase = j * 256 + wid * 64;
      int c = cbase + lane;
      int row = c >> 3;
      int kc = (c & 7) ^ (row & 7);
      gload16(Bt + (size_t)(bn + row) * ldb + k0 + kc * 8, Bd + cbase * 8);
    }
  };

  stage(0, 0);
  __syncthreads();
  int cur = 0;
  for (int t = 0; t < nt; ++t) {
    if (t + 1 < nt) stage(t + 1, cur ^ 1);   // prefetch next tile (other buffer)
    const u16* Asb = As + cur * (128 * 64);
    const u16* Bsb = Bs + cur * (BN * 64);
#pragma unroll
    for (int ks = 0; ks < 64; ks += 32) {
      short8 af[4], bfr[WN];
#pragma unroll
      for (int m = 0; m < 4; ++m) {
        int r = wr * 64 + m * 16 + (lane & 15);
        int ch = (lane >> 4) + (ks >> 3);
        af[m] = *(const short8*)&Asb[r * 64 + ((ch ^ (r & 7)) << 3)];
      }
#pragma unroll
      for (int n = 0; n < WN; ++n) {
        int r = wc * (BN / 2) + n * 16 + (lane & 15);
        int ch = (lane >> 4) + (ks >> 3);
        bfr[n] = *(const short8*)&Bsb[r * 64 + ((ch ^ (r & 7)) << 3)];
      }
#pragma unroll
      for (int m = 0; m < 4; ++m)
#pragma unroll
        for (int n = 0; n < WN; ++n)
          acc[m][n] = __builtin_amdgcn_mfma_f32_16x16x32_bf16(af[m], bfr[n], acc[m][n], 0, 0, 0);
    }
    __syncthreads();   // drains vmcnt(0): next tile landed; all waves done reading cur
    cur ^= 1;
  }

  const int fr = lane & 15, fq = lane >> 4;
#pragma unroll
  for (int m = 0; m < 4; ++m) {
#pragma unroll
    for (int n = 0; n < WN; ++n) {
#pragma unroll
      for (int j = 0; j < 4; ++j) {
        int row = bm + wr * 64 + m * 16 + fq * 4 + j;
        int col = bn + wc * (BN / 2) + n * 16 + fr;
        if (col < Nact) {
          float v = acc[m][n][j];
          if (ksegs == 1) {
            if (bias) v += bias[col];
            if (resid) v += resid[(size_t)row * ldr + col];
            if (act == 1) v = (v > 20.f) ? v : log1pf(__expf(v));  // softplus
            if (C) C[(size_t)row * ldc + col] = v;
            if (aux && col < auxN) aux[(size_t)row * auxN + col] = f2bf(v);
          } else {
            atomicAdd(&C[(size_t)row * ldc + col], v);
          }
        }
      }
    }
  }
}

// ---------------- causal depthwise conv (K=4) + silu -> bf16 ----------------
// input xz [B][S][4096] bf16, cols 0..2047 are xp
__global__ __launch_bounds__(256)
void conv_silu_kernel(const u16* __restrict__ xz, const float* __restrict__ w,
                      const float* __restrict__ cb, u16* __restrict__ xcb) {
  int idx = blockIdx.x * 256 + threadIdx.x;  // over CB*CS*CDI = 4M
  int d = idx & (CDI - 1);
  int t = (idx >> 11) & (CS - 1);
  int b = idx >> 21;
  const u16* col = xz + (size_t)b * CS * 4096 + d;
  float acc = cb[d];
#pragma unroll
  for (int k = 0; k < 4; ++k) {
    int tt = t - 3 + k;
    if (tt >= 0) acc = fmaf(bf2f(col[(size_t)tt * 4096]), w[d * 4 + k], acc);
  }
  float v = acc * (1.f / (1.f + __expf(-acc)));
  xcb[idx] = f2bf(v);
}

// ---------------- dbc[:,0:64] -> bf16 ----------------
__global__ __launch_bounds__(256)
void dtr_convert_kernel(const float* __restrict__ dbc, u16* __restrict__ dtrb) {
  int idx = blockIdx.x * 256 + threadIdx.x;  // 2048*64
  int r = idx >> 6, k = idx & 63;
  dtrb[idx] = f2bf(dbc[r * 96 + k]);
}

// ---------------- selective scan: thread per (b,chunk,d), N=16 in registers ----------------
__global__ __launch_bounds__(256)
void scan1_kernel(const u16* __restrict__ dtb, const u16* __restrict__ xcb,
                  const float* __restrict__ dbc, const float* __restrict__ A_log,
                  u16* __restrict__ P, u16* __restrict__ Q) {
  int gid = blockIdx.x * 256 + threadIdx.x;  // CB*CNC2*CDI = 262144
  int d = gid & (CDI - 1);
  int c = (gid >> 11) & (CNC2 - 1);
  int b = gid >> 17;
  float acoef[16];
#pragma unroll
  for (int j = 0; j < 4; ++j) {
    float4 al = ((const float4*)(A_log + d * 16))[j];
    acoef[j * 4 + 0] = -__expf(al.x);
    acoef[j * 4 + 1] = -__expf(al.y);
    acoef[j * 4 + 2] = -__expf(al.z);
    acoef[j * 4 + 3] = -__expf(al.w);
  }
  float Pv[16], Qv[16];
#pragma unroll
  for (int n = 0; n < 16; ++n) { Pv[n] = 1.f; Qv[n] = 0.f; }
  size_t rowbase = (size_t)b * CS + (size_t)c * CL2;
  for (int i = 0; i < CL2; ++i) {
    size_t r = rowbase + i;
    float dtv = bf2f(dtb[r * CDI + d]);
    float xcv = bf2f(xcb[r * CDI + d]);
    float dx = dtv * xcv;
    const float4* bs4 = (const float4*)(dbc + r * 96 + 64);
    float bs[16];
#pragma unroll
    for (int j = 0; j < 4; ++j) {
      float4 t4 = bs4[j];
      bs[j * 4 + 0] = t4.x; bs[j * 4 + 1] = t4.y; bs[j * 4 + 2] = t4.z; bs[j * 4 + 3] = t4.w;
    }
#pragma unroll
    for (int n = 0; n < 16; ++n) {
      float a = __expf(dtv * acoef[n]);
      Pv[n] *= a;
      Qv[n] = fmaf(a, Qv[n], dx * bs[n]);
    }
  }
  size_t o = (((size_t)b * CNC2 + c) * CDI + d) * 16;
  u16 pb[16], qb[16];
#pragma unroll
  for (int n = 0; n < 16; ++n) { pb[n] = f2bf(Pv[n]); qb[n] = f2bf(Qv[n]); }
#pragma unroll
  for (int j = 0; j < 2; ++j) {
    *(short8*)(P + o + j * 8) = *(short8*)(pb + j * 8);
    *(short8*)(Q + o + j * 8) = *(short8*)(qb + j * 8);
  }
}

// combine chunk summaries; rewrites Q in place with chunk-START state h0
__global__ __launch_bounds__(256)
void scan2_kernel(const u16* __restrict__ P, u16* __restrict__ Q) {
  int gid = blockIdx.x * 256 + threadIdx.x;  // CB*CDI*16 = 65536
  int n = gid & 15;
  int d = (gid >> 4) & (CDI - 1);
  int b = gid >> 15;
  float h = 0.f;
  for (int c = 0; c < CNC2; ++c) {
    size_t o = (((size_t)b * CNC2 + c) * CDI + d) * 16 + n;
    float p = bf2f(P[o]), q = bf2f(Q[o]);
    Q[o] = f2bf(h);
    h = fmaf(p, h, q);
  }
}

__global__ __launch_bounds__(256)
void scan3_kernel(const u16* __restrict__ dtb, const u16* __restrict__ xcb,
                  const float* __restrict__ dbc, const float* __restrict__ A_log,
                  const u16* __restrict__ Q, const u16* __restrict__ xz,
                  const float* __restrict__ Dskip, u16* __restrict__ y2b) {
  int gid = blockIdx.x * 256 + threadIdx.x;  // 262144
  int d = gid & (CDI - 1);
  int c = (gid >> 11) & (CNC2 - 1);
  int b = gid >> 17;
  float acoef[16];
#pragma unroll
  for (int j = 0; j < 4; ++j) {
    float4 al = ((const float4*)(A_log + d * 16))[j];
    acoef[j * 4 + 0] = -__expf(al.x);
    acoef[j * 4 + 1] = -__expf(al.y);
    acoef[j * 4 + 2] = -__expf(al.z);
    acoef[j * 4 + 3] = -__expf(al.w);
  }
  float h[16];
  size_t o = (((size_t)b * CNC2 + c) * CDI + d) * 16;
#pragma unroll
  for (int j = 0; j < 2; ++j) {
    short8 q8 = *(const short8*)(Q + o + j * 8);
#pragma unroll
    for (int n = 0; n < 8; ++n) h[j * 8 + n] = bf2f((u16)q8[n]);
  }
  float dsk = Dskip[d];
  size_t rowbase = (size_t)b * CS + (size_t)c * CL2;
  for (int i = 0; i < CL2; ++i) {
    size_t r = rowbase + i;
    float dtv = bf2f(dtb[r * CDI + d]);
    float xcv = bf2f(xcb[r * CDI + d]);
    float zv = bf2f(xz[r * 4096 + 2048 + d]);
    float dx = dtv * xcv;
    const float4* bc4 = (const float4*)(dbc + r * 96 + 64);
    float bs[16], cs[16];
#pragma unroll
    for (int j = 0; j < 4; ++j) {
      float4 t4 = bc4[j];
      bs[j * 4 + 0] = t4.x; bs[j * 4 + 1] = t4.y; bs[j * 4 + 2] = t4.z; bs[j * 4 + 3] = t4.w;
      float4 u4 = bc4[4 + j];
      cs[j * 4 + 0] = u4.x; cs[j * 4 + 1] = u4.y; cs[j * 4 + 2] = u4.z; cs[j * 4 + 3] = u4.w;
    }
    float y = 0.f;
#pragma unroll
    for (int n = 0; n < 16; ++n) {
      float a = __expf(dtv * acoef[n]);
      h[n] = fmaf(a, h[n], dx * bs[n]);
      y = fmaf(h[n], cs[n], y);
    }
    float sz = zv * (1.f / (1.f + __expf(-zv)));
    y2b[r * CDI + d] = f2bf((y + xcv * dsk) * sz);
  }
}

// ---------------- soliton stencil -> bf16 ----------------
__global__ __launch_bounds__(256)
void soliton_kernel(const float* __restrict__ uu, const float* __restrict__ gates,
                    const float* __restrict__ alpha, u16* __restrict__ sol) {
  int idx = blockIdx.x * 256 + threadIdx.x;  // CB*CS*CD = 2M
  int d = idx & (CD - 1);
  int t = (idx >> 10) & (CS - 1);
  int b = idx >> 20;
  int h = d >> 6;
  const float* base = uu + (size_t)b * CS * CD + d;
  int tm2 = max(t - 2, 0), tm1 = max(t - 1, 0);
  int tp1 = min(t + 1, CS - 1), tp2 = min(t + 2, CS - 1);
  float um2 = base[(size_t)tm2 * CD];
  float um1 = base[(size_t)tm1 * CD];
  float u0  = base[(size_t)t   * CD];
  float up1 = base[(size_t)tp1 * CD];
  float up2 = base[(size_t)tp2 * CD];
  float ux   = (up1 - um1) * 0.5f;
  float uxx  = up1 - 2.f * u0 + um1;
  float uxxx = (up2 - 2.f * up1 + 2.f * um1 - um2) * 0.5f;
  float sg = sinf(u0);
  float kdv = -6.f * u0 * ux - uxxx;
  float hj = (1.f + alpha[h] * u0) * uxx;
  float du = gates[h * 3 + 0] * sg + gates[h * 3 + 1] * kdv + gates[h * 3 + 2] * hj;
  sol[idx] = f2bf(0.1f * du);
}

extern "C" void kernel_launch(void* const* d_in, const int* in_sizes, int n_in,
                              void* d_out, int out_size, void* d_ws, size_t ws_size,
                              hipStream_t stream) {
  const float* x      = (const float*)d_in[0];
  const float* ln1_g  = (const float*)d_in[1];
  const float* ln1_b  = (const float*)d_in[2];
  const float* W_in   = (const float*)d_in[3];
  const float* b_in   = (const float*)d_in[4];
  const float* conv_w = (const float*)d_in[5];
  const float* conv_b = (const float*)d_in[6];
  const float* W_xp   = (const float*)d_in[7];
  const float* W_dt   = (const float*)d_in[8];
  const float* b_dt   = (const float*)d_in[9];
  const float* A_log  = (const float*)d_in[10];
  const float* D_skip = (const float*)d_in[11];
  const float* W_out  = (const float*)d_in[12];
  const float* b_out  = (const float*)d_in[13];
  const float* ln2_g  = (const float*)d_in[14];
  const float* ln2_b  = (const float*)d_in[15];
  const float* W_si   = (const float*)d_in[16];
  const float* b_si   = (const float*)d_in[17];
  const float* gates  = (const float*)d_in[18];
  const float* alpha  = (const float*)d_in[19];
  const float* W_so   = (const float*)d_in[20];
  const float* b_so   = (const float*)d_in[21];
  float* out = (float*)d_out;

  float* ws = (float*)d_ws;
  size_t off = 0;
  auto alloc = [&](size_t nwords) { float* p = ws + off; off += nwords; return p; };
  const size_t BS = (size_t)CB * CS;  // 2048 rows
  const size_t M1 = 1024 * 1024;

  u16* Wt_in  = (u16*)alloc(2 * M1);       // 4096x1024 bf16
  u16* Wt_xp  = (u16*)alloc(128 * 1024);   // 128x2048 bf16 (padded 96->128)
  u16* Wt_dt  = (u16*)alloc(64 * 1024);    // 2048x64 bf16
  u16* Wt_out = (u16*)alloc(M1);           // 1024x2048 bf16
  u16* Wt_si  = (u16*)alloc(M1 / 2);       // 1024x1024 bf16
  u16* Wt_so  = (u16*)alloc(M1 / 2);
  u16* u_bf   = (u16*)alloc(M1);           // 2048x1024 bf16; alias sol_bf
  u16* sol_bf = u_bf;
  u16* xz_bf  = (u16*)alloc(4 * M1);       // 2048x4096 bf16 (xp | z)
  u16* dt_bf  = (u16*)alloc(2 * M1);       // 2048x2048 bf16
  u16* xc_bf  = (u16*)alloc(2 * M1);       // 2048x2048 bf16
  float* dbc  = alloc(BS * 96);
  u16* dtr_bf = (u16*)alloc(64 * 1024);    // 2048x64 bf16
  u16* Pb     = (u16*)alloc(2 * M1);       // 2*64*2048*16 bf16 (8MB)
  u16* Qb     = (u16*)alloc(2 * M1);       // same; becomes h0 after scan2
  u16* y2_bf  = (u16*)alloc(2 * M1);       // 2048x2048 bf16
  float* uu   = (float*)Pb;                // 2048x1024 fp32 (8MB), Pb dead after scan2

  dim3 blk(256);

  // 0. weight transpose-converts (fp32 [K][N] -> bf16 [Npad][K])
  transpose_bf16_kernel<<<dim3(128, 32), blk, 0, stream>>>(W_in, Wt_in, 1024, 4096, 4096);
  transpose_bf16_kernel<<<dim3(4, 64), blk, 0, stream>>>(W_xp, Wt_xp, 2048, 96, 128);
  transpose_bf16_kernel<<<dim3(64, 2), blk, 0, stream>>>(W_dt, Wt_dt, 64, 2048, 2048);
  transpose_bf16_kernel<<<dim3(32, 64), blk, 0, stream>>>(W_out, Wt_out, 2048, 1024, 1024);
  transpose_bf16_kernel<<<dim3(32, 32), blk, 0, stream>>>(W_si, Wt_si, 1024, 1024, 1024);
  transpose_bf16_kernel<<<dim3(32, 32), blk, 0, stream>>>(W_so, Wt_so, 1024, 1024, 1024);

  // 1. u = LN1(x) -> bf16
  ln_kernel<<<BS, blk, 0, stream>>>(x, ln1_g, ln1_b, u_bf);
  // 2. xz = u @ W_in + b_in -> bf16 (both halves, N=4096; 512 blocks = 2/CU)
  gemm_bf16_kernel<128><<<dim3(32, 16), blk, 0, stream>>>(u_bf, 1024, Wt_in, 1024, b_in, nullptr, 0,
                                                          nullptr, 0, xz_bf, 4096, 4096, 1024, 0);
  // 3. xc = silu(conv(xp) + conv_b) -> bf16
  conv_silu_kernel<<<(BS * CDI) / 256, blk, 0, stream>>>(xz_bf, conv_w, conv_b, xc_bf);
  // 4. dbc = xc @ W_xp (N=96), split-K=8 with atomicAdd
  hipMemsetAsync(dbc, 0, BS * 96 * sizeof(float), stream);
  gemm_bf16_kernel<128><<<dim3(1, 16, 8), blk, 0, stream>>>(xc_bf, 2048, Wt_xp, 2048, nullptr, nullptr, 0,
                                                            dbc, 96, nullptr, 0, 96, 2048, 0);
  dtr_convert_kernel<<<(BS * 64) / 256, blk, 0, stream>>>(dbc, dtr_bf);
  // 5. dt = softplus(dtr @ W_dt + b_dt) -> bf16 (256 blocks)
  gemm_bf16_kernel<128><<<dim3(16, 16), blk, 0, stream>>>(dtr_bf, 64, Wt_dt, 64, b_dt, nullptr, 0,
                                                          nullptr, 0, dt_bf, 2048, 2048, 64, 1);
  // 6-8. chunked selective scan (N in registers)
  scan1_kernel<<<(CB * CNC2 * CDI) / 256, blk, 0, stream>>>(dt_bf, xc_bf, dbc, A_log, Pb, Qb);
  scan2_kernel<<<(CB * CDI * 16) / 256, blk, 0, stream>>>(Pb, Qb);
  scan3_kernel<<<(CB * CNC2 * CDI) / 256, blk, 0, stream>>>(dt_bf, xc_bf, dbc, A_log, Qb, xz_bf, D_skip, y2_bf);
  // 9. x1 = x + y2 @ W_out + b_out -> d_out (BN=64 -> 256 blocks)
  gemm_bf16_kernel<64><<<dim3(16, 16), blk, 0, stream>>>(y2_bf, 2048, Wt_out, 2048, b_out, x, 1024,
                                                         out, CD, nullptr, 0, 1024, 2048, 0);
  // 10. v = LN2(x1) -> bf16
  ln_kernel<<<BS, blk, 0, stream>>>(out, ln2_g, ln2_b, u_bf);
  // 11. uu = v @ W_si + b_si (fp32; aliases Pb which is dead)
  gemm_bf16_kernel<64><<<dim3(16, 16), blk, 0, stream>>>(u_bf, 1024, Wt_si, 1024, b_si, nullptr, 0,
                                                         uu, CD, nullptr, 0, 1024, 1024, 0);
  // 12. sol = 0.1 * du(uu) -> bf16 (aliases u_bf; gemm 11 already consumed it)
  soliton_kernel<<<(BS * CD) / 256, blk, 0, stream>>>(uu, gates, alpha, sol_bf);
  // 13. out = x1 + sol @ W_so + b_so
  gemm_bf16_kernel<64><<<dim3(16, 16), blk, 0, stream>>>(sol_bf, 1024, Wt_so, 1024, b_so, out, 1024,
                                                         out, CD, nullptr, 0, 1024, 1024, 0);
}